// Round 6
// baseline (874.967 us; speedup 1.0000x reference)
//
#include <hip/hip_runtime.h>
#include <hip/hip_bf16.h>

// ConvLayer: 3x3 s1 p1 conv, x=(256,512,512) f32, W=(3,3,256,256) HWIO, out=(256,512,512) f32.
// Strategy: bf16 implicit GEMM on MFMA.
//   xt layout: [h][cg4=ci/32][w][32ci]  (64B K-row contiguous in global)
//   wt layout: [kk][cg4][co][32ci]
//   conv_mfma r6: block 128co x 256w, 4 waves, WAVE TILE 64x128 (acc 4x8):
//     LDS fragment traffic 0.375 KB/MFMA (was 0.5) -- the r5 pipe analysis showed
//     LDS reads ~2x oversubscribed vs MFMA at 64x64 tiles.
//     Full double-buffer at EXACTLY 80KB (2 blocks/CU), halo pixels in regs
//     (Bs = 256 flat rows, no tail stage), chunk-XOR swizzle (BANK_CONFLICT=0 r5),
//     XCD h-banding (r1-proven), one barrier per K-step.

typedef __attribute__((ext_vector_type(8))) short bf16x8;
typedef __attribute__((ext_vector_type(4))) float floatx4;

#define HWSZ 262144   // 512*512
#define CIN  256
#define HH   512
#define WWD  512

__device__ __forceinline__ void async_copy16(const void* g, void* l) {
  __builtin_amdgcn_global_load_lds(
      (const __attribute__((address_space(1))) void*)g,
      (__attribute__((address_space(3))) void*)l, 16, 0, 0);
}

// ---------------- pass 1: x f32 [ci][h][w] -> xt bf16 [h][cg4][w][32] ----------------
// grid 1024 = 512 h x 2 w-halves; block 256 thr; no LDS.
__global__ __launch_bounds__(256) void convert_x(
    const float* __restrict__ x, __hip_bfloat16* __restrict__ xt)
{
  const int b  = blockIdx.x;           // 0..1023
  const int h  = b >> 1;
  const int wh = (b & 1) << 8;         // 0 or 256
  const int t  = threadIdx.x;
  const int q  = t >> 2;               // 0..63
  const int j  = t & 3;                // 16B chunk within pixel row
  const float* xbase = x + (size_t)h * WWD;
#pragma unroll 2
  for (int cg4 = 0; cg4 < 8; ++cg4) {
#pragma unroll
    for (int pass = 0; pass < 4; ++pass) {
      int w = wh + pass * 64 + q;
      const float* s = xbase + (size_t)(cg4 * 32 + j * 8) * HWSZ + w;
      unsigned int qw[4];
#pragma unroll
      for (int k = 0; k < 4; ++k) {
        float f0 = s[(size_t)(2 * k) * HWSZ];
        float f1 = s[(size_t)(2 * k + 1) * HWSZ];
        __hip_bfloat16 b0 = __float2bfloat16(f0);
        __hip_bfloat16 b1 = __float2bfloat16(f1);
        qw[k] = (unsigned int)*(const unsigned short*)&b0 |
                ((unsigned int)*(const unsigned short*)&b1 << 16);
      }
      uint4 v;
      v.x = qw[0]; v.y = qw[1]; v.z = qw[2]; v.w = qw[3];
      *(uint4*)&xt[(((size_t)h * 8 + cg4) << 14) + (w << 5) + (j << 3)] = v;
    }
  }
}

// ---------------- pass 2: W f32 [kh][kw][ci][co] -> wt bf16 [kk][cg4][co][32]; zero line ----
__global__ __launch_bounds__(256) void convert_w(
    const float* __restrict__ Wf, __hip_bfloat16* __restrict__ wt,
    __hip_bfloat16* __restrict__ zb)
{
  const int idx = blockIdx.x * 256 + threadIdx.x;   // < 589824
  const int ci = idx & 255;
  const int co = (idx >> 8) & 255;
  const int kk = idx >> 16;                          // 0..8
  wt[((((size_t)kk * 8 + (ci >> 5)) * 256 + co) << 5) + (ci & 31)] =
      __float2bfloat16(Wf[((size_t)(kk * 256 + ci) << 8) + co]);
  if (idx < 64) zb[idx] = __float2bfloat16(0.0f);
}

// ---------------- pass 3: MFMA implicit-GEMM conv ----------------
// grid 2048; block 256 thr = 4 waves (2 wm x 2 wn), wave tile 64co x 128w.
// XCD-banded swizzle: xcd = b&7 owns h-band [xcd*64, xcd*64+64).
__global__ __launch_bounds__(256, 2) void conv_mfma(
    const __hip_bfloat16* __restrict__ xt,   // [512][8][512][32]
    const __hip_bfloat16* __restrict__ wt,   // [9][8][256][32]
    const float* __restrict__ bias,
    float* __restrict__ out,                 // [256][512][512]
    const __hip_bfloat16* __restrict__ zb)
{
  __shared__ __align__(16) __hip_bfloat16 As[2][3 * 128 * 32];  // 49152 B
  __shared__ __align__(16) __hip_bfloat16 Bs[2][256 * 32];      // 32768 B (80KB total)

  const int b     = blockIdx.x;
  const int xcd   = b & 7;
  const int local = b >> 3;            // 0..255
  const int h     = (xcd << 6) + (local >> 2);
  const int rem   = local & 3;
  const int cot   = rem >> 1;
  const int wti   = rem & 1;
  const int w0    = wti << 8;          // 0 or 256
  const int co0   = cot << 7;
  const int t    = threadIdx.x;
  const int lane = t & 63;
  const int wave = t >> 6;
  const int wm   = wave & 1;    // co half (64) within 128
  const int wn   = wave >> 1;   // w half (128) within 256
  const int mcol = lane & 15;
  const int krow = lane >> 4;

  const int  wL   = w0 - 1;
  const int  wR   = w0 + 256;
  const bool wLok = (wL >= 0);
  const bool wRok = (wR < WWD);

  floatx4 acc[4][8];
#pragma unroll
  for (int mi = 0; mi < 4; ++mi)
#pragma unroll
    for (int ni = 0; ni < 8; ++ni) {
      floatx4 z = {0.f, 0.f, 0.f, 0.f};
      acc[mi][ni] = z;
    }

  // ---- stage s (s = kh*8 + cg4) into (Ad, Bd); halo chunks into *hl, *hr ----
  auto STAGE = [&](int s, __hip_bfloat16* Ad, __hip_bfloat16* Bd,
                   bf16x8* hl, bf16x8* hr) {
    const int kh  = s >> 3;
    const int cg4 = s & 7;
    const int hp  = h + kh - 1;
    const bool hok = (unsigned)hp < (unsigned)HH;
    const __hip_bfloat16* xp = xt + (((size_t)hp * 8 + cg4) << 14);
    // A: 3 kw x 128 co-rows x 64B = 1536 chunks (source chunk-XOR within 64B line)
#pragma unroll
    for (int rnd = 0; rnd < 6; ++rnd) {
      int c  = rnd * 256 + t;
      int kw = c >> 9;
      int m  = (c >> 2) & 127;
      int j  = c & 3;
      int js = j ^ ((m >> 1) & 3);
      const __hip_bfloat16* g =
          wt + ((((size_t)(kh * 3 + kw) * 8 + cg4) * 256 + co0 + m) << 5) + (js << 3);
      async_copy16(g, Ad + (c << 3));
    }
    // B: 256 w-rows x 64B = 1024 chunks; wp = w0+r always in [0,512) -> only hok check
#pragma unroll
    for (int rnd = 0; rnd < 4; ++rnd) {
      int c = rnd * 256 + t;
      int r = c >> 2;
      int j = c & 3;
      int js = j ^ ((r >> 1) & 3);
      const __hip_bfloat16* g = hok ? xp + ((w0 + r) << 5) + (js << 3)
                                    : zb + (js << 3);
      async_copy16(g, Bd + (c << 3));
    }
    // halo pixels (w0-1, w0+256): per-lane krow slice direct to regs
    const __hip_bfloat16* gl = (hok && wLok) ? xp + (wL << 5) + (krow << 3) : zb;
    const __hip_bfloat16* gr = (hok && wRok) ? xp + (wR << 5) + (krow << 3) : zb;
    *hl = *(const bf16x8*)gl;
    *hr = *(const bf16x8*)gr;
  };

  // ---- compute one K-step from (A, B) with halo regs ----
  auto COMPUTE = [&](const __hip_bfloat16* A, const __hip_bfloat16* B,
                     bf16x8 hl, bf16x8 hr) {
#pragma unroll
    for (int kw = 0; kw < 3; ++kw) {
      bf16x8 af[4], bfr[8];
#pragma unroll
      for (int mi = 0; mi < 4; ++mi) {
        int row = wm * 64 + mi * 16 + mcol;
        af[mi] = *(const bf16x8*)&A[(kw << 12) + (row << 5) +
                                    ((krow ^ ((row >> 1) & 3)) << 3)];
      }
#pragma unroll
      for (int ni = 0; ni < 8; ++ni) {
        int r  = wn * 128 + ni * 16 + mcol + kw - 1;   // -1..256
        int rc = r & 255;
        bfr[ni] = *(const bf16x8*)&B[(rc << 5) +
                                     ((krow ^ ((rc >> 1) & 3)) << 3)];
      }
      if (kw == 0) {                       // left edge: row -1 -> halo reg
        bool c = (wn == 0) && (mcol == 0);
        bfr[0] = c ? hl : bfr[0];
      }
      if (kw == 2) {                       // right edge: row 256 -> halo reg
        bool c = (wn == 1) && (mcol == 15);
        bfr[7] = c ? hr : bfr[7];
      }
#pragma unroll
      for (int mi = 0; mi < 4; ++mi)
#pragma unroll
        for (int ni = 0; ni < 8; ++ni)
          acc[mi][ni] = __builtin_amdgcn_mfma_f32_16x16x32_bf16(
              af[mi], bfr[ni], acc[mi][ni], 0, 0, 0);
    }
  };

  bf16x8 hl0, hr0, hl1, hr1;
  STAGE(0, As[0], Bs[0], &hl0, &hr0);
  __syncthreads();                          // drain + barrier

  for (int ss = 0; ss < 12; ++ss) {
    const int s = ss * 2;
    STAGE(s + 1, As[1], Bs[1], &hl1, &hr1); // prefetch odd stage
    COMPUTE(As[0], Bs[0], hl0, hr0);
    __syncthreads();
    if (s + 2 < 24) STAGE(s + 2, As[0], Bs[0], &hl0, &hr0);  // prefetch next even
    COMPUTE(As[1], Bs[1], hl1, hr1);
    __syncthreads();
  }

  // epilogue: D col = lane&15, row = (lane>>4)*4 + reg (m91-verified)
  const size_t outrow = (size_t)h * WWD;
#pragma unroll
  for (int mi = 0; mi < 4; ++mi) {
#pragma unroll
    for (int r = 0; r < 4; ++r) {
      int co = co0 + wm * 64 + mi * 16 + krow * 4 + r;
      float bv = bias[co];
      float* op = out + (size_t)co * HWSZ + outrow + w0 + wn * 128 + mcol;
#pragma unroll
      for (int ni = 0; ni < 8; ++ni)
        op[ni * 16] = acc[mi][ni][r] + bv;
    }
  }
}

// ---------------- fallback: naive fp32 direct conv (only if ws too small) ----------------
__global__ __launch_bounds__(256) void conv_naive(
    const float* __restrict__ x, const float* __restrict__ Wf,
    const float* __restrict__ bias, float* __restrict__ out)
{
  size_t idx = (size_t)blockIdx.x * 256 + threadIdx.x;
  int w  = (int)(idx & 511);
  int h  = (int)((idx >> 9) & 511);
  int co = (int)(idx >> 18);
  float acc = bias[co];
  for (int kh = 0; kh < 3; ++kh) {
    int hp = h + kh - 1;
    if ((unsigned)hp >= 512u) continue;
    for (int kw = 0; kw < 3; ++kw) {
      int wp = w + kw - 1;
      if ((unsigned)wp >= 512u) continue;
      const float* wcol = Wf + ((size_t)(kh * 3 + kw) << 16) + co;
      const float* xpix = x + (size_t)hp * 512 + wp;
      for (int ci = 0; ci < 256; ++ci)
        acc += xpix[(size_t)ci * HWSZ] * wcol[(size_t)ci << 8];
    }
  }
  out[idx] = acc;
}

extern "C" void kernel_launch(void* const* d_in, const int* in_sizes, int n_in,
                              void* d_out, int out_size, void* d_ws, size_t ws_size,
                              hipStream_t stream) {
  const float* x    = (const float*)d_in[0];
  const float* Wf   = (const float*)d_in[1];
  const float* bias = (const float*)d_in[2];
  float* out = (float*)d_out;

  const size_t xt_bytes = (size_t)HH * WWD * CIN * 2;        // 134217728
  const size_t wt_bytes = (size_t)9 * 256 * 256 * 2;         // 1179648
  const size_t need = xt_bytes + wt_bytes + 256;

  if (ws_size >= need) {
    __hip_bfloat16* xt = (__hip_bfloat16*)d_ws;
    __hip_bfloat16* wt = (__hip_bfloat16*)((char*)d_ws + xt_bytes);
    __hip_bfloat16* zb = (__hip_bfloat16*)((char*)d_ws + xt_bytes + wt_bytes);
    convert_x<<<1024, 256, 0, stream>>>(x, xt);
    convert_w<<<2304, 256, 0, stream>>>(Wf, wt, zb);
    conv_mfma<<<2048, 256, 0, stream>>>(xt, wt, bias, out, zb);
  } else {
    conv_naive<<<262144, 256, 0, stream>>>(x, Wf, bias, out);
  }
}